// Round 9
// baseline (400.270 us; speedup 1.0000x reference)
//
#include <hip/hip_runtime.h>
#include <cstdint>
#include <cmath>

#define BATCH 65536
#define NREAL 246
#define NPAD  256
#define K1    784
#define K1PAD 832
#define BINS  100
#define ALPHA 0.1f
#define RB    32
#define NBLK  (BATCH/RB)     // 2048

typedef __bf16 bf16x8 __attribute__((ext_vector_type(8)));
typedef __bf16 bf16x4 __attribute__((ext_vector_type(4)));
typedef float  f32x4  __attribute__((ext_vector_type(4)));

// LDS layout (bytes)
#define OFF_HS     0         // 32 rows * 512B = 16384
#define OFF_STAGE  16384     // L1 stage dbuf 2*4096 (union with hist)
#define OFF_HIST   16384     // 4 waves * 800 bins * 4B = 12800
#define OFF_MN     29184     // 32 rows * 4 waves * 4B = 512
#define OFF_MX     29696     // 512
#define OFF_LUT    30208     // 247 * 4B -> 1024
#define OFF_WENT   31232     // 4 waves * 6 layers * 4B = 96
#define LDS_TOTAL  31328

// ---------------- weight pad/convert: fp32 -> bf16, zero-padded ----------------
__global__ __launch_bounds__(256)
void pad_weights(const float* __restrict__ W1, const float* __restrict__ W2,
                 const float* __restrict__ W3, const float* __restrict__ W4,
                 const float* __restrict__ W5, const float* __restrict__ W6,
                 const float* __restrict__ W7,
                 __bf16* __restrict__ W1p, __bf16* __restrict__ Wp,
                 __bf16* __restrict__ W7p)
{
    int tid = blockIdx.x * 256 + threadIdx.x;
    const int n1 = NPAD * K1PAD;        // 212992
    const int n2 = 5 * NPAD * NPAD;     // 327680
    if (tid < n1) {
        int row = tid / K1PAD;
        int k   = tid - row * K1PAD;
        W1p[tid] = (__bf16)((row < NREAL && k < K1) ? W1[row * K1 + k] : 0.0f);
    } else if (tid < n1 + n2) {
        int t = tid - n1;
        int wsel = t >> 16;
        int idx  = t & 65535;
        int row  = idx >> 8, k = idx & 255;
        const float* W = (wsel == 0) ? W2 : (wsel == 1) ? W3 : (wsel == 2) ? W4
                        : (wsel == 3) ? W5 : W6;
        Wp[t] = (__bf16)((row < NREAL && k < NREAL) ? W[row * NREAL + k] : 0.0f);
    } else if (tid < n1 + n2 + 16 * NPAD) {
        int t = tid - n1 - n2;
        int row = t >> 8, k = t & 255;
        W7p[t] = (__bf16)((row < 10 && k < NREAL) ? W7[row * NREAL + k] : 0.0f);
    }
}

// ---------------- megakernel: 4 waves, 32 rows/block, 4+ blocks/CU ----------------
__global__ __launch_bounds__(256, 4)
void mega(const float* __restrict__ x,
          const __bf16* __restrict__ W1p,
          const __bf16* __restrict__ Wp,
          const __bf16* __restrict__ W7p,
          const float* __restrict__ b1, const float* __restrict__ b2,
          const float* __restrict__ b3, const float* __restrict__ b4,
          const float* __restrict__ b5, const float* __restrict__ b6,
          const float* __restrict__ b7,
          float* __restrict__ out, float* __restrict__ partial)
{
    __shared__ char smem[LDS_TOTAL];
    char*  Hb    = smem + OFF_HS;
    float* rowmn = (float*)(smem + OFF_MN);
    float* rowmx = (float*)(smem + OFF_MX);
    float* lut   = (float*)(smem + OFF_LUT);
    float* went  = (float*)(smem + OFF_WENT);

    const int tid = threadIdx.x;
    const int w = tid >> 6, l = tid & 63;
    const int lane16 = l & 15, lane4 = l >> 4;
    const int m0 = blockIdx.x * RB;

    // c*ln(c) LUT
    if (tid > 0 && tid < 247) lut[tid] = (float)tid * logf((float)tid);
    if (tid == 0) lut[0] = 0.0f;

    f32x4 acc[2][4];
#pragma unroll
    for (int i = 0; i < 2; ++i)
#pragma unroll
        for (int j = 0; j < 4; ++j) acc[i][j] = f32x4{0.f, 0.f, 0.f, 0.f};

    // wave w owns output cols [w*64, w*64+64); rows 0..31 shared by all waves
    // B fragment: half-K (kk) granularity -> only 16+16 VGPRs in flight
    auto loadBh = [&](bf16x8 (&dst)[4], const __bf16* Bbase, int Kb, int kt, int kk) {
        const __bf16* p = Bbase + (size_t)(w * 64 + lane16) * Kb + kt * 64 + kk * 32 + lane4 * 8;
#pragma unroll
        for (int j = 0; j < 4; ++j)
            dst[j] = *(const bf16x8*)(p + (size_t)j * 16 * Kb);
    };

    // one half-K MFMA step, A from swizzled LDS (base, rowStrideBytes template-ish)
    auto computeHalf = [&](const char* Ab, int rowStride, int kbyte, const bf16x8 (&bfr)[4]) {
#pragma unroll
        for (int i = 0; i < 2; ++i) {
            int row = i * 16 + lane16;
            bf16x8 af = *(const bf16x8*)(Ab + row * rowStride + ((kbyte + lane4 * 16) ^ ((row & 7) << 4)));
            __builtin_amdgcn_s_setprio(1);
#pragma unroll
            for (int j = 0; j < 4; ++j)
                acc[i][j] = __builtin_amdgcn_mfma_f32_16x16x32_bf16(af, bfr[j], acc[i][j], 0, 0, 0);
            __builtin_amdgcn_s_setprio(0);
        }
    };

    // ---------- epilogue: bias + leaky + swizzled Hs write + per-row min/max ----------
    auto epilogue = [&](const float* bias) {
        float bv[4];
#pragma unroll
        for (int j = 0; j < 4; ++j) {
            int col = w * 64 + j * 16 + lane16;
            bv[j] = (col < NREAL) ? bias[col] : 0.0f;
        }
#pragma unroll
        for (int i = 0; i < 2; ++i) {
#pragma unroll
            for (int rr = 0; rr < 4; ++rr) {
                int row = i * 16 + lane4 * 4 + rr;
                int swz = (row & 7) << 4;
                float mn = 1e30f, mx = -1e30f;
#pragma unroll
                for (int j = 0; j < 4; ++j) {
                    int col = w * 64 + j * 16 + lane16;
                    bool cv = col < NREAL;
                    float v = acc[i][j][rr] + bv[j];
                    v = v > 0.0f ? v : ALPHA * v;
                    *(__bf16*)(Hb + row * 512 + ((col * 2) ^ swz)) = cv ? (__bf16)v : (__bf16)0.0f;
                    mn = fminf(mn, cv ? v : 1e30f);
                    mx = fmaxf(mx, cv ? v : -1e30f);
                }
#pragma unroll
                for (int off = 1; off < 16; off <<= 1) {
                    mn = fminf(mn, __shfl_xor(mn, off, 64));
                    mx = fmaxf(mx, __shfl_xor(mx, off, 64));
                }
                if (lane16 == 0) {
                    rowmn[row * 4 + w] = mn;
                    rowmx[row * 4 + w] = mx;
                }
            }
        }
    };

    // ---------- entropy: wave w -> rows w*8..w*8+7; 8 lanes per row, no cross-lane fill ----------
    auto entropy = [&](int li) {
        int* histW = (int*)(smem + OFF_HIST) + w * 800;
        const int rg = l >> 3;            // row within wave's group
        const int q  = l & 7;             // lane within row
        const int row = w * 8 + rg;
        f32x4 m4 = *(const f32x4*)(rowmn + row * 4);
        f32x4 x4 = *(const f32x4*)(rowmx + row * 4);
        float mn = fminf(fminf(m4[0], m4[1]), fminf(m4[2], m4[3]));
        float mx = fmaxf(fmaxf(x4[0], x4[1]), fmaxf(x4[2], x4[3]));
        float rgv = mx - mn;
        float rs = (rgv > 0.0f) ? 100.0f / rgv : 0.0f;
#pragma unroll
        for (int t = 0; t < 13; ++t) { int b = t * 64 + l; if (b < 800) histW[b] = 0; }
        asm volatile("s_waitcnt lgkmcnt(0)" ::: "memory");
        const int swz = (row & 7) << 4;
#pragma unroll
        for (int t = 0; t < 8; ++t) {
            int c0 = q * 32 + t * 4;
            bf16x4 hv = *(const bf16x4*)(Hb + row * 512 + ((c0 * 2) ^ swz));
#pragma unroll
            for (int e = 0; e < 4; ++e) {
                if (c0 + e < NREAL) {
                    int idx = (int)floorf(((float)hv[e] - mn) * rs);
                    idx = idx < 0 ? 0 : (idx > BINS - 1 ? BINS - 1 : idx);
                    atomicAdd(&histW[rg * 100 + idx], 1);
                }
            }
        }
        asm volatile("s_waitcnt lgkmcnt(0)" ::: "memory");
        float S = 0.0f;
        const int rbase = rg * 100, tb = q * 13;
#pragma unroll
        for (int t = 0; t < 13; ++t) {
            int b = tb + t;
            if (b < 100) S += lut[histW[rbase + b]];
        }
#pragma unroll
        for (int off = 1; off < 64; off <<= 1) S += __shfl_xor(S, off, 64);
        if (l == 0) went[w * 6 + li] = 8.0f * logf(246.0f) - S * (1.0f / 246.0f);
    };

    bf16x8 curB[4], nxtB[4];

    // ================= layer 1: K=784 streamed from HBM via reg-relay stage =================
    {
        const int srow = tid >> 3;        // 0..31
        const int skc  = (tid & 7) * 8;   // k offset within 64
        float4 xr0, xr1;
        auto issueX = [&](int kt) {
            int k0 = kt * 64 + skc;
            if (k0 < K1) {                // 8-chunks fully valid (784 % 8 == 0)
                const float* gx = x + (size_t)(m0 + srow) * K1 + k0;
                xr0 = *(const float4*)gx;
                xr1 = *(const float4*)(gx + 4);
            } else {
                xr0 = float4{0.f,0.f,0.f,0.f};
                xr1 = float4{0.f,0.f,0.f,0.f};
            }
        };
        auto writeX = [&](int buf) {
            bf16x8 h;
            h[0]=(__bf16)xr0.x; h[1]=(__bf16)xr0.y; h[2]=(__bf16)xr0.z; h[3]=(__bf16)xr0.w;
            h[4]=(__bf16)xr1.x; h[5]=(__bf16)xr1.y; h[6]=(__bf16)xr1.z; h[7]=(__bf16)xr1.w;
            char* st = smem + OFF_STAGE + buf * 4096;
            *(bf16x8*)(st + srow * 128 + ((skc * 2) ^ ((srow & 7) << 4))) = h;
        };

        issueX(0);
        writeX(0);
        issueX(1);
        loadBh(curB, W1p, K1PAD, 0, 0);
        for (int kt = 0; kt < 13; ++kt) {
            __syncthreads();
            if (kt < 12) {
                writeX((kt + 1) & 1);
                if (kt < 11) issueX(kt + 2);
            }
            const char* st = smem + OFF_STAGE + (kt & 1) * 4096;
            loadBh(nxtB, W1p, K1PAD, kt, 1);
            computeHalf(st, 128, 0, curB);
            if (kt < 12) loadBh(curB, W1p, K1PAD, kt + 1, 0);
            computeHalf(st, 128, 64, nxtB);
        }
    }

    // ================= layers 2..6; entropy overlaps next GEMM across waves/blocks =================
    loadBh(curB, Wp, NPAD, 0, 0);     // prefetch layer-2 kt0/kk0 under epilogue+entropy
    epilogue(b1);
    __syncthreads();
    entropy(0);

    const float* bsel[5] = {b2, b3, b4, b5, b6};
    for (int li = 0; li < 5; ++li) {
        const __bf16* Bp = Wp + (size_t)li * (NPAD * NPAD);
#pragma unroll
        for (int i = 0; i < 2; ++i)
#pragma unroll
            for (int j = 0; j < 4; ++j) acc[i][j] = f32x4{0.f, 0.f, 0.f, 0.f};

#pragma unroll
        for (int kt = 0; kt < 4; ++kt) {
            loadBh(nxtB, Bp, NPAD, kt, 1);
            computeHalf(Hb, 512, kt * 128, curB);
            if (kt < 3)      loadBh(curB, Bp, NPAD, kt + 1, 0);
            else if (li < 4) loadBh(curB, Bp + NPAD * NPAD, NPAD, 0, 0);
            computeHalf(Hb, 512, kt * 128 + 64, nxtB);
        }

        __syncthreads();       // all waves done reading Hs (GEMM + prior entropy)
        epilogue(bsel[li]);
        __syncthreads();       // new Hs + minmax visible
        entropy(li + 1);       // no barrier after: next GEMM only reads Hs
    }

    // ================= head: waves 0..1, one 16-row MFMA strip each =================
    if (w < 2) {
        f32x4 hacc = f32x4{0.f, 0.f, 0.f, 0.f};
        int row = w * 16 + lane16;
#pragma unroll
        for (int kt = 0; kt < 8; ++kt) {
            bf16x8 af = *(const bf16x8*)(Hb + row * 512 + ((kt * 64 + lane4 * 16) ^ ((row & 7) << 4)));
            bf16x8 bf = *(const bf16x8*)(W7p + (size_t)lane16 * NPAD + kt * 32 + lane4 * 8);
            hacc = __builtin_amdgcn_mfma_f32_16x16x32_bf16(af, bf, hacc, 0, 0, 0);
        }
        float bv = (lane16 < 10) ? b7[lane16] : 0.0f;
#pragma unroll
        for (int r = 0; r < 4; ++r) {
            float lg = fmaxf(hacc[r] + bv, 0.0f);
            float vm = (lane16 < 10) ? lg : -1e30f;
#pragma unroll
            for (int off = 8; off; off >>= 1) vm = fmaxf(vm, __shfl_xor(vm, off, 64));
            float ex = (lane16 < 10) ? expf(lg - vm) : 0.0f;
#pragma unroll
            for (int off = 8; off; off >>= 1) ex += __shfl_xor(ex, off, 64);
            float ls = vm + logf(ex);
            if (lane16 < 10) {
                int grow = m0 + w * 16 + lane4 * 4 + r;
                out[(size_t)grow * 10 + lane16] = lg - ls;
            }
        }
    }

    __syncthreads();
    if (tid < 6) {
        float s = 0.0f;
#pragma unroll
        for (int q = 0; q < 4; ++q) s += went[q * 6 + tid];
        partial[tid * NBLK + blockIdx.x] = s;
    }
}

// ---------------- final entropy mean (deterministic fixed-order) ----------------
__global__ __launch_bounds__(256)
void reduce_kernel(const float* __restrict__ partial, float* __restrict__ out)
{
    __shared__ float s[256];
    const int li = blockIdx.x, tid = threadIdx.x;
    float a = 0.0f;
    for (int i = tid; i < NBLK; i += 256) a += partial[li * NBLK + i];
    s[tid] = a;
    __syncthreads();
    for (int st = 128; st; st >>= 1) {
        if (tid < st) s[tid] += s[tid + st];
        __syncthreads();
    }
    if (tid == 0)
        out[(size_t)BATCH * 10 + li] = s[0] / (float)BATCH + logf((float)BINS);
}

// ---------------- launch ----------------
extern "C" void kernel_launch(void* const* d_in, const int* in_sizes, int n_in,
                              void* d_out, int out_size, void* d_ws, size_t ws_size,
                              hipStream_t stream)
{
    (void)in_sizes; (void)n_in; (void)out_size; (void)ws_size;

    const float* x  = (const float*)d_in[0];
    const float* W1 = (const float*)d_in[1];
    const float* b1 = (const float*)d_in[2];
    const float* W2 = (const float*)d_in[3];
    const float* b2 = (const float*)d_in[4];
    const float* W3 = (const float*)d_in[5];
    const float* b3 = (const float*)d_in[6];
    const float* W4 = (const float*)d_in[7];
    const float* b4 = (const float*)d_in[8];
    const float* W5 = (const float*)d_in[9];
    const float* b5 = (const float*)d_in[10];
    const float* W6 = (const float*)d_in[11];
    const float* b6 = (const float*)d_in[12];
    const float* W7 = (const float*)d_in[13];
    const float* b7 = (const float*)d_in[14];

    char* ws = (char*)d_ws;
    // ws layout (bytes):
    //   0       : W1p  256*832 bf16   = 425984
    //   425984  : Wp   5*256*256 bf16 = 655360
    //   1081344 : W7p  16*256 bf16    = 8192
    //   1089536 : partial 6*2048 f32  = 49152
    __bf16* W1p = (__bf16*)(ws);
    __bf16* Wp  = (__bf16*)(ws + 425984);
    __bf16* W7p = (__bf16*)(ws + 1081344);
    float*  partial = (float*)(ws + 1089536);
    float*  out = (float*)d_out;

    pad_weights<<<2128, 256, 0, stream>>>(W1, W2, W3, W4, W5, W6, W7, W1p, Wp, W7p);
    mega<<<NBLK, 256, 0, stream>>>(x, W1p, Wp, W7p, b1, b2, b3, b4, b5, b6, b7, out, partial);
    reduce_kernel<<<6, 256, 0, stream>>>(partial, out);
}

// Round 10
// 325.748 us; speedup vs baseline: 1.2288x; 1.2288x over previous
//
#include <hip/hip_runtime.h>
#include <cstdint>
#include <cmath>

#define BATCH 65536
#define NREAL 246
#define NPAD  256
#define K1    784
#define K1PAD 832
#define BINS  100
#define ALPHA 0.1f
#define RB    32
#define NBLK  (BATCH/RB)     // 2048

typedef __bf16 bf16x8 __attribute__((ext_vector_type(8)));
typedef __bf16 bf16x4 __attribute__((ext_vector_type(4)));
typedef float  f32x4  __attribute__((ext_vector_type(4)));

// LDS layout (bytes)
#define OFF_HS     0         // 32 rows * 512B = 16384
#define OFF_STAGE  16384     // L1 stage dbuf 2*4096 (union with hist)
#define OFF_HIST   16384     // 4 waves * 800 bins * 4B = 12800
#define OFF_MN     29184     // 32 rows * 4 waves * 4B = 512
#define OFF_MX     29696     // 512
#define OFF_LUT    30208     // 247 * 4B -> 1024
#define OFF_WENT   31232     // 4 waves * 6 layers * 4B = 96
#define LDS_TOTAL  31328

// ---------------- weight pad/convert: fp32 -> bf16, zero-padded ----------------
__global__ __launch_bounds__(256)
void pad_weights(const float* __restrict__ W1, const float* __restrict__ W2,
                 const float* __restrict__ W3, const float* __restrict__ W4,
                 const float* __restrict__ W5, const float* __restrict__ W6,
                 const float* __restrict__ W7,
                 __bf16* __restrict__ W1p, __bf16* __restrict__ Wp,
                 __bf16* __restrict__ W7p)
{
    int tid = blockIdx.x * 256 + threadIdx.x;
    const int n1 = NPAD * K1PAD;        // 212992
    const int n2 = 5 * NPAD * NPAD;     // 327680
    if (tid < n1) {
        int row = tid / K1PAD;
        int k   = tid - row * K1PAD;
        W1p[tid] = (__bf16)((row < NREAL && k < K1) ? W1[row * K1 + k] : 0.0f);
    } else if (tid < n1 + n2) {
        int t = tid - n1;
        int wsel = t >> 16;
        int idx  = t & 65535;
        int row  = idx >> 8, k = idx & 255;
        const float* W = (wsel == 0) ? W2 : (wsel == 1) ? W3 : (wsel == 2) ? W4
                        : (wsel == 3) ? W5 : W6;
        Wp[t] = (__bf16)((row < NREAL && k < NREAL) ? W[row * NREAL + k] : 0.0f);
    } else if (tid < n1 + n2 + 16 * NPAD) {
        int t = tid - n1 - n2;
        int row = t >> 8, k = t & 255;
        W7p[t] = (__bf16)((row < 10 && k < NREAL) ? W7[row * NREAL + k] : 0.0f);
    }
}

// ---------------- megakernel: 4 waves, 32 rows/block; NO reg cap (spills cost more than occupancy) ----------------
__global__ __launch_bounds__(256)
void mega(const float* __restrict__ x,
          const __bf16* __restrict__ W1p,
          const __bf16* __restrict__ Wp,
          const __bf16* __restrict__ W7p,
          const float* __restrict__ b1, const float* __restrict__ b2,
          const float* __restrict__ b3, const float* __restrict__ b4,
          const float* __restrict__ b5, const float* __restrict__ b6,
          const float* __restrict__ b7,
          float* __restrict__ out, float* __restrict__ partial)
{
    __shared__ char smem[LDS_TOTAL];
    char*  Hb    = smem + OFF_HS;
    float* rowmn = (float*)(smem + OFF_MN);
    float* rowmx = (float*)(smem + OFF_MX);
    float* lut   = (float*)(smem + OFF_LUT);
    float* went  = (float*)(smem + OFF_WENT);

    const int tid = threadIdx.x;
    const int w = tid >> 6, l = tid & 63;
    const int lane16 = l & 15, lane4 = l >> 4;
    const int m0 = blockIdx.x * RB;

    // c*ln(c) LUT
    if (tid > 0 && tid < 247) lut[tid] = (float)tid * logf((float)tid);
    if (tid == 0) lut[0] = 0.0f;

    f32x4 acc[2][4];
#pragma unroll
    for (int i = 0; i < 2; ++i)
#pragma unroll
        for (int j = 0; j < 4; ++j) acc[i][j] = f32x4{0.f, 0.f, 0.f, 0.f};

    // wave w owns output cols [w*64, w*64+64); rows 0..31 shared by all waves
    // B fragment: half-K (kk) granularity -> only 16+16 VGPRs in flight
    auto loadBh = [&](bf16x8 (&dst)[4], const __bf16* Bbase, int Kb, int kt, int kk) {
        const __bf16* p = Bbase + (size_t)(w * 64 + lane16) * Kb + kt * 64 + kk * 32 + lane4 * 8;
#pragma unroll
        for (int j = 0; j < 4; ++j)
            dst[j] = *(const bf16x8*)(p + (size_t)j * 16 * Kb);
    };

    // one half-K MFMA step, A from swizzled LDS
    auto computeHalf = [&](const char* Ab, int rowStride, int kbyte, const bf16x8 (&bfr)[4]) {
#pragma unroll
        for (int i = 0; i < 2; ++i) {
            int row = i * 16 + lane16;
            bf16x8 af = *(const bf16x8*)(Ab + row * rowStride + ((kbyte + lane4 * 16) ^ ((row & 7) << 4)));
            __builtin_amdgcn_s_setprio(1);
#pragma unroll
            for (int j = 0; j < 4; ++j)
                acc[i][j] = __builtin_amdgcn_mfma_f32_16x16x32_bf16(af, bfr[j], acc[i][j], 0, 0, 0);
            __builtin_amdgcn_s_setprio(0);
        }
    };

    // ---------- epilogue: bias + leaky + swizzled Hs write + per-row min/max ----------
    auto epilogue = [&](const float* bias) {
        float bv[4];
#pragma unroll
        for (int j = 0; j < 4; ++j) {
            int col = w * 64 + j * 16 + lane16;
            bv[j] = (col < NREAL) ? bias[col] : 0.0f;
        }
#pragma unroll
        for (int i = 0; i < 2; ++i) {
#pragma unroll
            for (int rr = 0; rr < 4; ++rr) {
                int row = i * 16 + lane4 * 4 + rr;
                int swz = (row & 7) << 4;
                float mn = 1e30f, mx = -1e30f;
#pragma unroll
                for (int j = 0; j < 4; ++j) {
                    int col = w * 64 + j * 16 + lane16;
                    bool cv = col < NREAL;
                    float v = acc[i][j][rr] + bv[j];
                    v = v > 0.0f ? v : ALPHA * v;
                    *(__bf16*)(Hb + row * 512 + ((col * 2) ^ swz)) = cv ? (__bf16)v : (__bf16)0.0f;
                    mn = fminf(mn, cv ? v : 1e30f);
                    mx = fmaxf(mx, cv ? v : -1e30f);
                }
#pragma unroll
                for (int off = 1; off < 16; off <<= 1) {
                    mn = fminf(mn, __shfl_xor(mn, off, 64));
                    mx = fmaxf(mx, __shfl_xor(mx, off, 64));
                }
                if (lane16 == 0) {
                    rowmn[row * 4 + w] = mn;
                    rowmx[row * 4 + w] = mx;
                }
            }
        }
    };

    // ---------- entropy: wave w -> rows w*8..w*8+7; 8 lanes per row, no cross-lane fill ----------
    auto entropy = [&](int li) {
        int* histW = (int*)(smem + OFF_HIST) + w * 800;
        const int rg = l >> 3;            // row within wave's group
        const int q  = l & 7;             // lane within row
        const int row = w * 8 + rg;
        f32x4 m4 = *(const f32x4*)(rowmn + row * 4);
        f32x4 x4 = *(const f32x4*)(rowmx + row * 4);
        float mn = fminf(fminf(m4[0], m4[1]), fminf(m4[2], m4[3]));
        float mx = fmaxf(fmaxf(x4[0], x4[1]), fmaxf(x4[2], x4[3]));
        float rgv = mx - mn;
        float rs = (rgv > 0.0f) ? 100.0f / rgv : 0.0f;
#pragma unroll
        for (int t = 0; t < 13; ++t) { int b = t * 64 + l; if (b < 800) histW[b] = 0; }
        asm volatile("s_waitcnt lgkmcnt(0)" ::: "memory");
        const int swz = (row & 7) << 4;
#pragma unroll
        for (int t = 0; t < 8; ++t) {
            int c0 = q * 32 + t * 4;
            bf16x4 hv = *(const bf16x4*)(Hb + row * 512 + ((c0 * 2) ^ swz));
#pragma unroll
            for (int e = 0; e < 4; ++e) {
                if (c0 + e < NREAL) {
                    int idx = (int)floorf(((float)hv[e] - mn) * rs);
                    idx = idx < 0 ? 0 : (idx > BINS - 1 ? BINS - 1 : idx);
                    atomicAdd(&histW[rg * 100 + idx], 1);
                }
            }
        }
        asm volatile("s_waitcnt lgkmcnt(0)" ::: "memory");
        float S = 0.0f;
        const int rbase = rg * 100, tb = q * 13;
#pragma unroll
        for (int t = 0; t < 13; ++t) {
            int b = tb + t;
            if (b < 100) S += lut[histW[rbase + b]];
        }
#pragma unroll
        for (int off = 1; off < 64; off <<= 1) S += __shfl_xor(S, off, 64);
        if (l == 0) went[w * 6 + li] = 8.0f * logf(246.0f) - S * (1.0f / 246.0f);
    };

    bf16x8 curB[4], nxtB[4];

    // ================= layer 1: K=784 streamed from HBM via reg-relay stage =================
    {
        const int srow = tid >> 3;        // 0..31
        const int skc  = (tid & 7) * 8;   // k offset within 64
        float4 xr0, xr1;
        auto issueX = [&](int kt) {
            int k0 = kt * 64 + skc;
            if (k0 < K1) {                // 8-chunks fully valid (784 % 8 == 0)
                const float* gx = x + (size_t)(m0 + srow) * K1 + k0;
                xr0 = *(const float4*)gx;
                xr1 = *(const float4*)(gx + 4);
            } else {
                xr0 = float4{0.f,0.f,0.f,0.f};
                xr1 = float4{0.f,0.f,0.f,0.f};
            }
        };
        auto writeX = [&](int buf) {
            bf16x8 h;
            h[0]=(__bf16)xr0.x; h[1]=(__bf16)xr0.y; h[2]=(__bf16)xr0.z; h[3]=(__bf16)xr0.w;
            h[4]=(__bf16)xr1.x; h[5]=(__bf16)xr1.y; h[6]=(__bf16)xr1.z; h[7]=(__bf16)xr1.w;
            char* st = smem + OFF_STAGE + buf * 4096;
            *(bf16x8*)(st + srow * 128 + ((skc * 2) ^ ((srow & 7) << 4))) = h;
        };

        issueX(0);
        writeX(0);
        issueX(1);
        loadBh(curB, W1p, K1PAD, 0, 0);
        for (int kt = 0; kt < 13; ++kt) {
            __syncthreads();
            if (kt < 12) {
                writeX((kt + 1) & 1);
                if (kt < 11) issueX(kt + 2);
            }
            const char* st = smem + OFF_STAGE + (kt & 1) * 4096;
            loadBh(nxtB, W1p, K1PAD, kt, 1);
            computeHalf(st, 128, 0, curB);
            if (kt < 12) loadBh(curB, W1p, K1PAD, kt + 1, 0);
            computeHalf(st, 128, 64, nxtB);
        }
    }

    // ================= layers 2..6; entropy overlaps next GEMM across waves/blocks =================
    loadBh(curB, Wp, NPAD, 0, 0);     // prefetch layer-2 kt0/kk0 under epilogue+entropy
    epilogue(b1);
    __syncthreads();
    entropy(0);

    const float* bsel[5] = {b2, b3, b4, b5, b6};
    for (int li = 0; li < 5; ++li) {
        const __bf16* Bp = Wp + (size_t)li * (NPAD * NPAD);
#pragma unroll
        for (int i = 0; i < 2; ++i)
#pragma unroll
            for (int j = 0; j < 4; ++j) acc[i][j] = f32x4{0.f, 0.f, 0.f, 0.f};

#pragma unroll
        for (int kt = 0; kt < 4; ++kt) {
            loadBh(nxtB, Bp, NPAD, kt, 1);
            computeHalf(Hb, 512, kt * 128, curB);
            if (kt < 3)      loadBh(curB, Bp, NPAD, kt + 1, 0);
            else if (li < 4) loadBh(curB, Bp + NPAD * NPAD, NPAD, 0, 0);
            computeHalf(Hb, 512, kt * 128 + 64, nxtB);
        }

        __syncthreads();       // all waves done reading Hs (GEMM + prior entropy)
        epilogue(bsel[li]);
        __syncthreads();       // new Hs + minmax visible
        entropy(li + 1);       // no barrier after: next GEMM only reads Hs
    }

    // ================= head: waves 0..1, one 16-row MFMA strip each =================
    if (w < 2) {
        f32x4 hacc = f32x4{0.f, 0.f, 0.f, 0.f};
        int row = w * 16 + lane16;
#pragma unroll
        for (int kt = 0; kt < 8; ++kt) {
            bf16x8 af = *(const bf16x8*)(Hb + row * 512 + ((kt * 64 + lane4 * 16) ^ ((row & 7) << 4)));
            bf16x8 bf = *(const bf16x8*)(W7p + (size_t)lane16 * NPAD + kt * 32 + lane4 * 8);
            hacc = __builtin_amdgcn_mfma_f32_16x16x32_bf16(af, bf, hacc, 0, 0, 0);
        }
        float bv = (lane16 < 10) ? b7[lane16] : 0.0f;
#pragma unroll
        for (int r = 0; r < 4; ++r) {
            float lg = fmaxf(hacc[r] + bv, 0.0f);
            float vm = (lane16 < 10) ? lg : -1e30f;
#pragma unroll
            for (int off = 8; off; off >>= 1) vm = fmaxf(vm, __shfl_xor(vm, off, 64));
            float ex = (lane16 < 10) ? expf(lg - vm) : 0.0f;
#pragma unroll
            for (int off = 8; off; off >>= 1) ex += __shfl_xor(ex, off, 64);
            float ls = vm + logf(ex);
            if (lane16 < 10) {
                int grow = m0 + w * 16 + lane4 * 4 + r;
                out[(size_t)grow * 10 + lane16] = lg - ls;
            }
        }
    }

    __syncthreads();
    if (tid < 6) {
        float s = 0.0f;
#pragma unroll
        for (int q = 0; q < 4; ++q) s += went[q * 6 + tid];
        partial[tid * NBLK + blockIdx.x] = s;
    }
}

// ---------------- final entropy mean (deterministic fixed-order) ----------------
__global__ __launch_bounds__(256)
void reduce_kernel(const float* __restrict__ partial, float* __restrict__ out)
{
    __shared__ float s[256];
    const int li = blockIdx.x, tid = threadIdx.x;
    float a = 0.0f;
    for (int i = tid; i < NBLK; i += 256) a += partial[li * NBLK + i];
    s[tid] = a;
    __syncthreads();
    for (int st = 128; st; st >>= 1) {
        if (tid < st) s[tid] += s[tid + st];
        __syncthreads();
    }
    if (tid == 0)
        out[(size_t)BATCH * 10 + li] = s[0] / (float)BATCH + logf((float)BINS);
}

// ---------------- launch ----------------
extern "C" void kernel_launch(void* const* d_in, const int* in_sizes, int n_in,
                              void* d_out, int out_size, void* d_ws, size_t ws_size,
                              hipStream_t stream)
{
    (void)in_sizes; (void)n_in; (void)out_size; (void)ws_size;

    const float* x  = (const float*)d_in[0];
    const float* W1 = (const float*)d_in[1];
    const float* b1 = (const float*)d_in[2];
    const float* W2 = (const float*)d_in[3];
    const float* b2 = (const float*)d_in[4];
    const float* W3 = (const float*)d_in[5];
    const float* b3 = (const float*)d_in[6];
    const float* W4 = (const float*)d_in[7];
    const float* b4 = (const float*)d_in[8];
    const float* W5 = (const float*)d_in[9];
    const float* b5 = (const float*)d_in[10];
    const float* W6 = (const float*)d_in[11];
    const float* b6 = (const float*)d_in[12];
    const float* W7 = (const float*)d_in[13];
    const float* b7 = (const float*)d_in[14];

    char* ws = (char*)d_ws;
    // ws layout (bytes):
    //   0       : W1p  256*832 bf16   = 425984
    //   425984  : Wp   5*256*256 bf16 = 655360
    //   1081344 : W7p  16*256 bf16    = 8192
    //   1089536 : partial 6*2048 f32  = 49152
    __bf16* W1p = (__bf16*)(ws);
    __bf16* Wp  = (__bf16*)(ws + 425984);
    __bf16* W7p = (__bf16*)(ws + 1081344);
    float*  partial = (float*)(ws + 1089536);
    float*  out = (float*)d_out;

    pad_weights<<<2128, 256, 0, stream>>>(W1, W2, W3, W4, W5, W6, W7, W1p, Wp, W7p);
    mega<<<NBLK, 256, 0, stream>>>(x, W1p, Wp, W7p, b1, b2, b3, b4, b5, b6, b7, out, partial);
    reduce_kernel<<<6, 256, 0, stream>>>(partial, out);
}

// Round 11
// 297.275 us; speedup vs baseline: 1.3465x; 1.0958x over previous
//
#include <hip/hip_runtime.h>
#include <cstdint>
#include <cmath>

#define BATCH 65536
#define NREAL 246
#define NPAD  256
#define K1    784
#define K1PAD 832
#define BINS  100
#define ALPHA 0.1f
#define RB    32
#define NBLK  (BATCH/RB)     // 2048

typedef __bf16 bf16x8 __attribute__((ext_vector_type(8)));
typedef __bf16 bf16x4 __attribute__((ext_vector_type(4)));
typedef float  f32x4  __attribute__((ext_vector_type(4)));

// LDS layout (bytes)
#define OFF_HS     0         // 32 rows * 512B = 16384
#define OFF_STAGE  16384     // L1 stage dbuf 2*4096 (union with hist)
#define OFF_HIST   16384     // 32 rows * 100 bins * 4B = 12800 (shared, after L1)
#define OFF_MN     29184     // 32 rows * 4 waves * 4B = 512
#define OFF_MX     29696     // 512
#define OFF_LUT    30208     // 247 * 4B -> 1024
#define OFF_WENT   31232     // 4 waves * 6 layers * 4B = 96
#define LDS_TOTAL  31328

// ---------------- weight/bias pad/convert ----------------
__global__ __launch_bounds__(256)
void pad_weights(const float* __restrict__ W1, const float* __restrict__ W2,
                 const float* __restrict__ W3, const float* __restrict__ W4,
                 const float* __restrict__ W5, const float* __restrict__ W6,
                 const float* __restrict__ W7,
                 const float* __restrict__ b1, const float* __restrict__ b2,
                 const float* __restrict__ b3, const float* __restrict__ b4,
                 const float* __restrict__ b5, const float* __restrict__ b6,
                 __bf16* __restrict__ W1p, __bf16* __restrict__ Wp,
                 __bf16* __restrict__ W7p, float* __restrict__ bpad)
{
    int tid = blockIdx.x * 256 + threadIdx.x;
    const int n1 = NPAD * K1PAD;        // 212992
    const int n2 = 5 * NPAD * NPAD;     // 327680
    const int n3 = 16 * NPAD;           // 4096
    if (tid < n1) {
        int row = tid / K1PAD;
        int k   = tid - row * K1PAD;
        W1p[tid] = (__bf16)((row < NREAL && k < K1) ? W1[row * K1 + k] : 0.0f);
    } else if (tid < n1 + n2) {
        int t = tid - n1;
        int wsel = t >> 16;
        int idx  = t & 65535;
        int row  = idx >> 8, k = idx & 255;
        const float* W = (wsel == 0) ? W2 : (wsel == 1) ? W3 : (wsel == 2) ? W4
                        : (wsel == 3) ? W5 : W6;
        Wp[t] = (__bf16)((row < NREAL && k < NREAL) ? W[row * NREAL + k] : 0.0f);
    } else if (tid < n1 + n2 + n3) {
        int t = tid - n1 - n2;
        int row = t >> 8, k = t & 255;
        W7p[t] = (__bf16)((row < 10 && k < NREAL) ? W7[row * NREAL + k] : 0.0f);
    } else if (tid < n1 + n2 + n3 + 6 * NPAD) {
        int t = tid - n1 - n2 - n3;
        int li = t >> 8, k = t & 255;
        const float* b = (li == 0) ? b1 : (li == 1) ? b2 : (li == 2) ? b3
                        : (li == 3) ? b4 : (li == 4) ? b5 : b6;
        bpad[t] = (k < NREAL) ? b[k] : 0.0f;
    }
}

// ---------------- megakernel: 4 waves, 32 rows/block ----------------
__global__ __launch_bounds__(256)
void mega(const float* __restrict__ x,
          const __bf16* __restrict__ W1p,
          const __bf16* __restrict__ Wp,
          const __bf16* __restrict__ W7p,
          const float* __restrict__ bpad,
          const float* __restrict__ b7,
          float* __restrict__ out, float* __restrict__ partial)
{
    __shared__ char smem[LDS_TOTAL];
    char*  Hb    = smem + OFF_HS;
    float* rowmn = (float*)(smem + OFF_MN);
    float* rowmx = (float*)(smem + OFF_MX);
    float* lut   = (float*)(smem + OFF_LUT);
    float* went  = (float*)(smem + OFF_WENT);
    int*   hist  = (int*)(smem + OFF_HIST);

    const int tid = threadIdx.x;
    const int w = tid >> 6, l = tid & 63;
    const int lane16 = l & 15, lane4 = l >> 4;
    const int m0 = blockIdx.x * RB;

    // c*ln(c) LUT
    if (tid > 0 && tid < 247) lut[tid] = (float)tid * logf((float)tid);
    if (tid == 0) lut[0] = 0.0f;

    f32x4 acc[2][4];
#pragma unroll
    for (int i = 0; i < 2; ++i)
#pragma unroll
        for (int j = 0; j < 4; ++j) acc[i][j] = f32x4{0.f, 0.f, 0.f, 0.f};

    // W fragment (first mfma operand): row n = w*64 + j*16 + lane16, k-slice by lane4
    auto loadBh = [&](bf16x8 (&dst)[4], const __bf16* Bbase, int Kb, int kt, int kk) {
        const __bf16* p = Bbase + (size_t)(w * 64 + lane16) * Kb + kt * 64 + kk * 32 + lane4 * 8;
#pragma unroll
        for (int j = 0; j < 4; ++j)
            dst[j] = *(const bf16x8*)(p + (size_t)j * 16 * Kb);
    };

    // half-K step: acc[i][j] = mfma(W, H) -> D[n in (lane4,reg), m in lane16]
    auto computeHalf = [&](const char* Ab, int rowStride, int kbyte, const bf16x8 (&bfr)[4]) {
#pragma unroll
        for (int i = 0; i < 2; ++i) {
            int row = i * 16 + lane16;
            bf16x8 af = *(const bf16x8*)(Ab + row * rowStride + ((kbyte + lane4 * 16) ^ ((row & 7) << 4)));
            __builtin_amdgcn_s_setprio(1);
#pragma unroll
            for (int j = 0; j < 4; ++j)
                acc[i][j] = __builtin_amdgcn_mfma_f32_16x16x32_bf16(bfr[j], af, acc[i][j], 0, 0, 0);
            __builtin_amdgcn_s_setprio(0);
        }
    };

    // ---------- epilogue: bias+leaky, packed b64 Hs write, in-lane minmax; keeps f32 in acc ----------
    auto epilogue = [&](const float* bp) {
        f32x4 bq[4];
#pragma unroll
        for (int j = 0; j < 4; ++j)
            bq[j] = *(const f32x4*)(bp + w * 64 + j * 16 + lane4 * 4);
#pragma unroll
        for (int i = 0; i < 2; ++i) {
            const int m = i * 16 + lane16;
            const int swz = (m & 7) << 4;
            float mn = 1e30f, mx = -1e30f;
#pragma unroll
            for (int j = 0; j < 4; ++j) {
                const int nbase = w * 64 + j * 16 + lane4 * 4;
                bf16x4 hv;
#pragma unroll
                for (int r = 0; r < 4; ++r) {
                    float v = acc[i][j][r] + bq[j][r];
                    v = v > 0.0f ? v : ALPHA * v;
                    bool valid = (nbase + r) < NREAL;
                    hv[r] = valid ? (__bf16)v : (__bf16)0.0f;
                    acc[i][j][r] = v;                       // f32 kept for entropy fill
                    mn = fminf(mn, valid ? v : 1e30f);
                    mx = fmaxf(mx, valid ? v : -1e30f);
                }
                *(bf16x4*)(Hb + m * 512 + ((nbase * 2) ^ swz)) = hv;   // ds_write_b64
            }
            mn = fminf(mn, __shfl_xor(mn, 16, 64));
            mx = fmaxf(mx, __shfl_xor(mx, 16, 64));
            mn = fminf(mn, __shfl_xor(mn, 32, 64));
            mx = fmaxf(mx, __shfl_xor(mx, 32, 64));
            if (lane4 == 0) {
                rowmn[m * 4 + w] = mn;
                rowmx[m * 4 + w] = mx;
            }
        }
    };

    // ---------- entropy pieces ----------
    auto ezero = [&]() {
        int4* hz = (int4*)hist;                 // 800 int4
        const int4 z = int4{0, 0, 0, 0};
        hz[tid] = z; hz[tid + 256] = z; hz[tid + 512] = z;
        if (tid < 32) hz[tid + 768] = z;
    };
    auto efill = [&]() {
#pragma unroll
        for (int i = 0; i < 2; ++i) {
            const int m = i * 16 + lane16;
            f32x4 m4 = *(const f32x4*)(rowmn + m * 4);
            f32x4 x4 = *(const f32x4*)(rowmx + m * 4);
            float mn = fminf(fminf(m4[0], m4[1]), fminf(m4[2], m4[3]));
            float mx = fmaxf(fmaxf(x4[0], x4[1]), fmaxf(x4[2], x4[3]));
            float rgv = mx - mn;
            float rs = (rgv > 0.0f) ? 100.0f / rgv : 0.0f;
            int* hrow = hist + m * 100;
#pragma unroll
            for (int j = 0; j < 4; ++j) {
                const int nbase = w * 64 + j * 16 + lane4 * 4;
#pragma unroll
                for (int r = 0; r < 4; ++r) {
                    if (nbase + r < NREAL) {
                        int idx = (int)floorf((acc[i][j][r] - mn) * rs);
                        idx = idx < 0 ? 0 : (idx > BINS - 1 ? BINS - 1 : idx);
                        atomicAdd(&hrow[idx], 1);
                    }
                }
            }
        }
    };
    auto esum = [&](int li) {
        const int rg = l >> 3, q = l & 7;
        const int row = w * 8 + rg;
        float S = 0.0f;
#pragma unroll
        for (int t = 0; t < 13; ++t) {
            int b = q * 13 + t;
            if (b < 100) S += lut[hist[row * 100 + b]];
        }
#pragma unroll
        for (int off = 1; off < 64; off <<= 1) S += __shfl_xor(S, off, 64);
        if (l == 0) went[w * 6 + li] = 8.0f * logf(246.0f) - S * (1.0f / 246.0f);
    };

    bf16x8 curB[4], nxtB[4];

    // ================= layer 1: K=784 streamed from HBM via reg-relay stage =================
    {
        const int srow = tid >> 3;        // 0..31
        const int skc  = (tid & 7) * 8;   // k offset within 64
        float4 xr0, xr1;
        auto issueX = [&](int kt) {
            int k0 = kt * 64 + skc;
            if (k0 < K1) {                // 8-chunks fully valid (784 % 8 == 0)
                const float* gx = x + (size_t)(m0 + srow) * K1 + k0;
                xr0 = *(const float4*)gx;
                xr1 = *(const float4*)(gx + 4);
            } else {
                xr0 = float4{0.f,0.f,0.f,0.f};
                xr1 = float4{0.f,0.f,0.f,0.f};
            }
        };
        auto writeX = [&](int buf) {
            bf16x8 h;
            h[0]=(__bf16)xr0.x; h[1]=(__bf16)xr0.y; h[2]=(__bf16)xr0.z; h[3]=(__bf16)xr0.w;
            h[4]=(__bf16)xr1.x; h[5]=(__bf16)xr1.y; h[6]=(__bf16)xr1.z; h[7]=(__bf16)xr1.w;
            char* st = smem + OFF_STAGE + buf * 4096;
            *(bf16x8*)(st + srow * 128 + ((skc * 2) ^ ((srow & 7) << 4))) = h;
        };

        issueX(0);
        writeX(0);
        issueX(1);
        loadBh(curB, W1p, K1PAD, 0, 0);
        for (int kt = 0; kt < 13; ++kt) {
            __syncthreads();
            if (kt < 12) {
                writeX((kt + 1) & 1);
                if (kt < 11) issueX(kt + 2);
            }
            const char* st = smem + OFF_STAGE + (kt & 1) * 4096;
            loadBh(nxtB, W1p, K1PAD, kt, 1);
            computeHalf(st, 128, 0, curB);
            if (kt < 12) loadBh(curB, W1p, K1PAD, kt + 1, 0);
            computeHalf(st, 128, 64, nxtB);
        }
    }

    // L1 tail: prefetch layer-2 B, epilogue; then hist (stage region) is safe to zero
    loadBh(curB, Wp, NPAD, 0, 0);
    epilogue(bpad);                 // layer-1 bias = bpad + 0
    __syncthreads();                // stage reads done (all waves) + Hs/minmax visible
    ezero();
    __syncthreads();                // hist zeroed
    efill();
    __syncthreads();                // atomics done
    esum(0);

    // ================= layers 2..6 =================
    for (int li = 0; li < 5; ++li) {
        const __bf16* Bp = Wp + (size_t)li * (NPAD * NPAD);
#pragma unroll
        for (int i = 0; i < 2; ++i)
#pragma unroll
            for (int j = 0; j < 4; ++j) acc[i][j] = f32x4{0.f, 0.f, 0.f, 0.f};

#pragma unroll
        for (int kt = 0; kt < 4; ++kt) {
            loadBh(nxtB, Bp, NPAD, kt, 1);
            computeHalf(Hb, 512, kt * 128, curB);
            if (kt < 3)      loadBh(curB, Bp, NPAD, kt + 1, 0);
            else if (li < 4) loadBh(curB, Bp + NPAD * NPAD, NPAD, 0, 0);
            computeHalf(Hb, 512, kt * 128 + 64, nxtB);
        }

        __syncthreads();            // Hs reads done (all waves) + prior esum done
        ezero();
        epilogue(bpad + (li + 1) * NPAD);
        __syncthreads();            // hist zeroed + Hs/minmax visible
        efill();
        __syncthreads();            // atomics done
        esum(li + 1);               // next GEMM only reads Hs -> no barrier needed
    }

    // ================= head: waves 0..1, one 16-row MFMA strip each =================
    if (w < 2) {
        f32x4 hacc = f32x4{0.f, 0.f, 0.f, 0.f};
        int row = w * 16 + lane16;
#pragma unroll
        for (int kt = 0; kt < 8; ++kt) {
            bf16x8 af = *(const bf16x8*)(Hb + row * 512 + ((kt * 64 + lane4 * 16) ^ ((row & 7) << 4)));
            bf16x8 bf = *(const bf16x8*)(W7p + (size_t)lane16 * NPAD + kt * 32 + lane4 * 8);
            hacc = __builtin_amdgcn_mfma_f32_16x16x32_bf16(af, bf, hacc, 0, 0, 0);
        }
        float bv = (lane16 < 10) ? b7[lane16] : 0.0f;
#pragma unroll
        for (int r = 0; r < 4; ++r) {
            float lg = fmaxf(hacc[r] + bv, 0.0f);
            float vm = (lane16 < 10) ? lg : -1e30f;
#pragma unroll
            for (int off = 8; off; off >>= 1) vm = fmaxf(vm, __shfl_xor(vm, off, 64));
            float ex = (lane16 < 10) ? expf(lg - vm) : 0.0f;
#pragma unroll
            for (int off = 8; off; off >>= 1) ex += __shfl_xor(ex, off, 64);
            float ls = vm + logf(ex);
            if (lane16 < 10) {
                int grow = m0 + w * 16 + lane4 * 4 + r;
                out[(size_t)grow * 10 + lane16] = lg - ls;
            }
        }
    }

    __syncthreads();
    if (tid < 6) {
        float s = 0.0f;
#pragma unroll
        for (int q = 0; q < 4; ++q) s += went[q * 6 + tid];
        partial[tid * NBLK + blockIdx.x] = s;
    }
}

// ---------------- final entropy mean (deterministic fixed-order) ----------------
__global__ __launch_bounds__(256)
void reduce_kernel(const float* __restrict__ partial, float* __restrict__ out)
{
    __shared__ float s[256];
    const int li = blockIdx.x, tid = threadIdx.x;
    float a = 0.0f;
    for (int i = tid; i < NBLK; i += 256) a += partial[li * NBLK + i];
    s[tid] = a;
    __syncthreads();
    for (int st = 128; st; st >>= 1) {
        if (tid < st) s[tid] += s[tid + st];
        __syncthreads();
    }
    if (tid == 0)
        out[(size_t)BATCH * 10 + li] = s[0] / (float)BATCH + logf((float)BINS);
}

// ---------------- launch ----------------
extern "C" void kernel_launch(void* const* d_in, const int* in_sizes, int n_in,
                              void* d_out, int out_size, void* d_ws, size_t ws_size,
                              hipStream_t stream)
{
    (void)in_sizes; (void)n_in; (void)out_size; (void)ws_size;

    const float* x  = (const float*)d_in[0];
    const float* W1 = (const float*)d_in[1];
    const float* b1 = (const float*)d_in[2];
    const float* W2 = (const float*)d_in[3];
    const float* b2 = (const float*)d_in[4];
    const float* W3 = (const float*)d_in[5];
    const float* b3 = (const float*)d_in[6];
    const float* W4 = (const float*)d_in[7];
    const float* b4 = (const float*)d_in[8];
    const float* W5 = (const float*)d_in[9];
    const float* b5 = (const float*)d_in[10];
    const float* W6 = (const float*)d_in[11];
    const float* b6 = (const float*)d_in[12];
    const float* W7 = (const float*)d_in[13];
    const float* b7 = (const float*)d_in[14];

    char* ws = (char*)d_ws;
    // ws layout (bytes):
    //   0       : W1p  256*832 bf16   = 425984
    //   425984  : Wp   5*256*256 bf16 = 655360
    //   1081344 : W7p  16*256 bf16    = 8192
    //   1089536 : bpad 6*256 f32      = 6144
    //   1095680 : partial 6*2048 f32  = 49152
    __bf16* W1p = (__bf16*)(ws);
    __bf16* Wp  = (__bf16*)(ws + 425984);
    __bf16* W7p = (__bf16*)(ws + 1081344);
    float*  bpad = (float*)(ws + 1089536);
    float*  partial = (float*)(ws + 1095680);
    float*  out = (float*)d_out;

    pad_weights<<<2134, 256, 0, stream>>>(W1, W2, W3, W4, W5, W6, W7,
                                          b1, b2, b3, b4, b5, b6,
                                          W1p, Wp, W7p, bpad);
    mega<<<NBLK, 256, 0, stream>>>(x, W1p, Wp, W7p, bpad, b7, out, partial);
    reduce_kernel<<<6, 256, 0, stream>>>(partial, out);
}

// Round 12
// 289.913 us; speedup vs baseline: 1.3807x; 1.0254x over previous
//
#include <hip/hip_runtime.h>
#include <cstdint>
#include <cmath>

#define BATCH 65536
#define NREAL 246
#define NPAD  256
#define K1    784
#define K1PAD 832
#define BINS  100
#define ALPHA 0.1f
#define RB    64
#define NBLK  (BATCH/RB)     // 1024

typedef __bf16 bf16x8 __attribute__((ext_vector_type(8)));
typedef __bf16 bf16x4 __attribute__((ext_vector_type(4)));
typedef float  f32x4  __attribute__((ext_vector_type(4)));

// LDS layout (bytes)
#define OFF_HS     0         // 64 rows * 512B = 32768
#define OFF_STAGE  32768     // L1 stage dbuf 2*8192 = 16384 (union with hist)
#define OFF_HIST   32768     // 64 rows * 100 bins * 4B = 25600
#define OFF_MN     58368     // 64 rows * 4 waves * 4B = 1024
#define OFF_MX     59392     // 1024
#define OFF_LUT    60416     // 247 * 4B -> 1024
#define OFF_WENT   61440     // 4 waves * 6 layers * 4B -> 128
#define LDS_TOTAL  61568     // ~61.5 KB -> 2 blocks/CU

// ---------------- weight/bias pad/convert ----------------
__global__ __launch_bounds__(256)
void pad_weights(const float* __restrict__ W1, const float* __restrict__ W2,
                 const float* __restrict__ W3, const float* __restrict__ W4,
                 const float* __restrict__ W5, const float* __restrict__ W6,
                 const float* __restrict__ W7,
                 const float* __restrict__ b1, const float* __restrict__ b2,
                 const float* __restrict__ b3, const float* __restrict__ b4,
                 const float* __restrict__ b5, const float* __restrict__ b6,
                 __bf16* __restrict__ W1p, __bf16* __restrict__ Wp,
                 __bf16* __restrict__ W7p, float* __restrict__ bpad)
{
    int tid = blockIdx.x * 256 + threadIdx.x;
    const int n1 = NPAD * K1PAD;        // 212992
    const int n2 = 5 * NPAD * NPAD;     // 327680
    const int n3 = 16 * NPAD;           // 4096
    if (tid < n1) {
        int row = tid / K1PAD;
        int k   = tid - row * K1PAD;
        W1p[tid] = (__bf16)((row < NREAL && k < K1) ? W1[row * K1 + k] : 0.0f);
    } else if (tid < n1 + n2) {
        int t = tid - n1;
        int wsel = t >> 16;
        int idx  = t & 65535;
        int row  = idx >> 8, k = idx & 255;
        const float* W = (wsel == 0) ? W2 : (wsel == 1) ? W3 : (wsel == 2) ? W4
                        : (wsel == 3) ? W5 : W6;
        Wp[t] = (__bf16)((row < NREAL && k < NREAL) ? W[row * NREAL + k] : 0.0f);
    } else if (tid < n1 + n2 + n3) {
        int t = tid - n1 - n2;
        int row = t >> 8, k = t & 255;
        W7p[t] = (__bf16)((row < 10 && k < NREAL) ? W7[row * NREAL + k] : 0.0f);
    } else if (tid < n1 + n2 + n3 + 6 * NPAD) {
        int t = tid - n1 - n2 - n3;
        int li = t >> 8, k = t & 255;
        const float* b = (li == 0) ? b1 : (li == 1) ? b2 : (li == 2) ? b3
                        : (li == 3) ? b4 : (li == 4) ? b5 : b6;
        bpad[t] = (k < NREAL) ? b[k] : 0.0f;
    }
}

// ---------------- megakernel: 4 waves, 64 rows/block, whole-layer B in registers ----------------
__global__ __launch_bounds__(256)
void mega(const float* __restrict__ x,
          const __bf16* __restrict__ W1p,
          const __bf16* __restrict__ Wp,
          const __bf16* __restrict__ W7p,
          const float* __restrict__ bpad,
          const float* __restrict__ b7,
          float* __restrict__ out, float* __restrict__ partial)
{
    __shared__ char smem[LDS_TOTAL];
    char*  Hb    = smem + OFF_HS;
    float* rowmn = (float*)(smem + OFF_MN);
    float* rowmx = (float*)(smem + OFF_MX);
    float* lut   = (float*)(smem + OFF_LUT);
    float* went  = (float*)(smem + OFF_WENT);
    int*   hist  = (int*)(smem + OFF_HIST);

    const int tid = threadIdx.x;
    const int w = tid >> 6, l = tid & 63;
    const int lane16 = l & 15, lane4 = l >> 4;
    const int m0 = blockIdx.x * RB;

    if (tid < 247) lut[tid] = (tid > 0) ? (float)tid * logf((float)tid) : 0.0f;

    f32x4 acc[4][4];
#pragma unroll
    for (int i = 0; i < 4; ++i)
#pragma unroll
        for (int j = 0; j < 4; ++j) acc[i][j] = f32x4{0.f, 0.f, 0.f, 0.f};

    bf16x8 Ball[8][4];      // full 64-col x 256-K weight panel (128 VGPRs)

    // issue the whole next layer's weight panel (32 x global_load_dwordx4)
    auto loadAll = [&](const __bf16* Bbase) {
        const __bf16* p = Bbase + (size_t)(w * 64 + lane16) * NPAD + lane4 * 8;
#pragma unroll
        for (int h = 0; h < 8; ++h)
#pragma unroll
            for (int j = 0; j < 4; ++j)
                Ball[h][j] = *(const bf16x8*)(p + j * 16 * NPAD + h * 32);
    };

    // mid-layer GEMM: pure register/LDS stream, 128 MFMAs
    auto gemmMid = [&]() {
#pragma unroll
        for (int h = 0; h < 8; ++h) {
            bf16x8 af[4];
#pragma unroll
            for (int i = 0; i < 4; ++i) {
                int m = i * 16 + lane16;
                af[i] = *(const bf16x8*)(Hb + m * 512 + ((h * 64 + lane4 * 16) ^ ((m & 7) << 4)));
            }
            __builtin_amdgcn_s_setprio(1);
#pragma unroll
            for (int i = 0; i < 4; ++i)
#pragma unroll
                for (int j = 0; j < 4; ++j)
                    acc[i][j] = __builtin_amdgcn_mfma_f32_16x16x32_bf16(Ball[h][j], af[i], acc[i][j], 0, 0, 0);
            __builtin_amdgcn_s_setprio(0);
        }
    };

    // bias + leaky, packed b64 Hs write, in-lane minmax; keeps f32 in acc for efill
    auto epilogue = [&](const float* bp) {
        f32x4 bq[4];
#pragma unroll
        for (int j = 0; j < 4; ++j)
            bq[j] = *(const f32x4*)(bp + w * 64 + j * 16 + lane4 * 4);
#pragma unroll
        for (int i = 0; i < 4; ++i) {
            const int m = i * 16 + lane16;
            const int swz = (m & 7) << 4;
            float mn = 1e30f, mx = -1e30f;
#pragma unroll
            for (int j = 0; j < 4; ++j) {
                const int nbase = w * 64 + j * 16 + lane4 * 4;
                bf16x4 hv;
#pragma unroll
                for (int r = 0; r < 4; ++r) {
                    float v = acc[i][j][r] + bq[j][r];
                    v = v > 0.0f ? v : ALPHA * v;
                    bool valid = (nbase + r) < NREAL;
                    hv[r] = valid ? (__bf16)v : (__bf16)0.0f;
                    acc[i][j][r] = v;
                    mn = fminf(mn, valid ? v : 1e30f);
                    mx = fmaxf(mx, valid ? v : -1e30f);
                }
                *(bf16x4*)(Hb + m * 512 + ((nbase * 2) ^ swz)) = hv;
            }
            mn = fminf(mn, __shfl_xor(mn, 16, 64));
            mx = fmaxf(mx, __shfl_xor(mx, 16, 64));
            mn = fminf(mn, __shfl_xor(mn, 32, 64));
            mx = fmaxf(mx, __shfl_xor(mx, 32, 64));
            if (lane4 == 0) { rowmn[m * 4 + w] = mn; rowmx[m * 4 + w] = mx; }
        }
    };

    auto ezero = [&]() {
        int4* hz = (int4*)hist;                 // 1600 int4
        const int4 z = int4{0, 0, 0, 0};
#pragma unroll
        for (int t = 0; t < 6; ++t) hz[tid + t * 256] = z;
        if (tid < 64) hz[1536 + tid] = z;
    };

    auto efill = [&]() {
#pragma unroll
        for (int i = 0; i < 4; ++i) {
            const int m = i * 16 + lane16;
            f32x4 m4 = *(const f32x4*)(rowmn + m * 4);
            f32x4 x4v = *(const f32x4*)(rowmx + m * 4);
            float mn = fminf(fminf(m4[0], m4[1]), fminf(m4[2], m4[3]));
            float mx = fmaxf(fmaxf(x4v[0], x4v[1]), fmaxf(x4v[2], x4v[3]));
            float rgv = mx - mn;
            float rs = (rgv > 0.0f) ? 100.0f / rgv : 0.0f;
            int* hrow = hist + m * 100;
#pragma unroll
            for (int j = 0; j < 4; ++j) {
                const int nbase = w * 64 + j * 16 + lane4 * 4;
#pragma unroll
                for (int r = 0; r < 4; ++r) {
                    if (nbase + r < NREAL) {
                        int idx = (int)floorf((acc[i][j][r] - mn) * rs);
                        idx = idx < 0 ? 0 : (idx > BINS - 1 ? BINS - 1 : idx);
                        atomicAdd(&hrow[idx], 1);
                    }
                }
            }
        }
    };

    auto esum = [&](int li) {
        const int rg = l >> 2, q = l & 3;          // 16 rows/wave, 4 lanes/row
        const int row = w * 16 + rg;
        const int* hrow = hist + row * 100 + q * 25;
        float S = 0.0f;
#pragma unroll
        for (int t = 0; t < 25; ++t) S += lut[hrow[t]];
#pragma unroll
        for (int off = 1; off < 64; off <<= 1) S += __shfl_xor(S, off, 64);
        if (l == 0) went[w * 6 + li] = 16.0f * logf(246.0f) - S * (1.0f / 246.0f);
    };

    // ================= layer 1: K=784 streamed from HBM via reg-relay stage =================
    {
        const int srow = tid >> 2;        // 0..63
        const int skq  = tid & 3;         // 16-elem k chunk
        float4 xr[4];
        auto issueX = [&](int kt) {
            int k0 = kt * 64 + skq * 16;
            if (k0 < K1) {                // 784 % 16 == 0 -> chunk fully valid or fully pad
                const float* gx = x + (size_t)(m0 + srow) * K1 + k0;
#pragma unroll
                for (int q = 0; q < 4; ++q) xr[q] = *(const float4*)(gx + q * 4);
            } else {
#pragma unroll
                for (int q = 0; q < 4; ++q) xr[q] = float4{0.f, 0.f, 0.f, 0.f};
            }
        };
        auto writeX = [&](int buf) {
            bf16x8 h0, h1;
            h0[0]=(__bf16)xr[0].x; h0[1]=(__bf16)xr[0].y; h0[2]=(__bf16)xr[0].z; h0[3]=(__bf16)xr[0].w;
            h0[4]=(__bf16)xr[1].x; h0[5]=(__bf16)xr[1].y; h0[6]=(__bf16)xr[1].z; h0[7]=(__bf16)xr[1].w;
            h1[0]=(__bf16)xr[2].x; h1[1]=(__bf16)xr[2].y; h1[2]=(__bf16)xr[2].z; h1[3]=(__bf16)xr[2].w;
            h1[4]=(__bf16)xr[3].x; h1[5]=(__bf16)xr[3].y; h1[6]=(__bf16)xr[3].z; h1[7]=(__bf16)xr[3].w;
            char* st = smem + OFF_STAGE + buf * 8192;
            const int swz = (srow & 7) << 4;
            *(bf16x8*)(st + srow * 128 + ((skq * 32)      ^ swz)) = h0;
            *(bf16x8*)(st + srow * 128 + ((skq * 32 + 16) ^ swz)) = h1;
        };

        bf16x8 A0[4], A1[4], B0[4], B1[4];   // static dbuf names (no runtime reg-array index)
        auto loadKt = [&](bf16x8 (&C0)[4], bf16x8 (&C1)[4], int kt) {
            const __bf16* p = W1p + (size_t)(w * 64 + lane16) * K1PAD + kt * 64 + lane4 * 8;
#pragma unroll
            for (int j = 0; j < 4; ++j) {
                C0[j] = *(const bf16x8*)(p + (size_t)j * 16 * K1PAD);
                C1[j] = *(const bf16x8*)(p + (size_t)j * 16 * K1PAD + 32);
            }
        };
        auto l1c = [&](const char* st, const bf16x8 (&C0)[4], const bf16x8 (&C1)[4]) {
#pragma unroll
            for (int kk = 0; kk < 2; ++kk) {
                bf16x8 af[4];
#pragma unroll
                for (int i = 0; i < 4; ++i) {
                    int m = i * 16 + lane16;
                    af[i] = *(const bf16x8*)(st + m * 128 + ((kk * 64 + lane4 * 16) ^ ((m & 7) << 4)));
                }
                __builtin_amdgcn_s_setprio(1);
#pragma unroll
                for (int i = 0; i < 4; ++i)
#pragma unroll
                    for (int j = 0; j < 4; ++j)
                        acc[i][j] = __builtin_amdgcn_mfma_f32_16x16x32_bf16(kk ? C1[j] : C0[j], af[i], acc[i][j], 0, 0, 0);
                __builtin_amdgcn_s_setprio(0);
            }
        };

        issueX(0); writeX(0); issueX(1);
        loadKt(A0, A1, 0);
        for (int kt = 0; kt < 13; ++kt) {
            __syncthreads();
            if (kt < 12) { writeX((kt + 1) & 1); if (kt < 11) issueX(kt + 2); }
            const char* st = smem + OFF_STAGE + (kt & 1) * 8192;
            if ((kt & 1) == 0) { if (kt < 12) loadKt(B0, B1, kt + 1); l1c(st, A0, A1); }
            else               { if (kt < 12) loadKt(A0, A1, kt + 1); l1c(st, B0, B1); }
        }
    }

    // L1 tail: issue layer-2 weight panel; it flies under epilogue+entropy
    loadAll(Wp);
    epilogue(bpad);
    __syncthreads();            // stage reads done (all waves) + Hs/minmax visible
    ezero();
    __syncthreads();
    efill();
    __syncthreads();
    esum(0);

    // ================= layers 2..6 =================
    for (int li = 0; li < 5; ++li) {
#pragma unroll
        for (int i = 0; i < 4; ++i)
#pragma unroll
            for (int j = 0; j < 4; ++j) acc[i][j] = f32x4{0.f, 0.f, 0.f, 0.f};

        gemmMid();
        if (li < 4) loadAll(Wp + (size_t)(li + 1) * NPAD * NPAD);   // next panel in flight

        __syncthreads();        // Hs reads done (all waves); prior esum hist reads done
        ezero();
        epilogue(bpad + (li + 1) * NPAD);
        __syncthreads();        // hist zeroed + Hs/minmax visible
        efill();
        __syncthreads();        // atomics done
        esum(li + 1);           // next GEMM only reads Hs -> no barrier after
    }

    // ================= head: 4 waves, one 16-row MFMA strip each =================
    {
        f32x4 hacc = f32x4{0.f, 0.f, 0.f, 0.f};
        int row = w * 16 + lane16;
#pragma unroll
        for (int kt = 0; kt < 8; ++kt) {
            bf16x8 af = *(const bf16x8*)(Hb + row * 512 + ((kt * 64 + lane4 * 16) ^ ((row & 7) << 4)));
            bf16x8 bf = *(const bf16x8*)(W7p + (size_t)lane16 * NPAD + kt * 32 + lane4 * 8);
            hacc = __builtin_amdgcn_mfma_f32_16x16x32_bf16(af, bf, hacc, 0, 0, 0);
        }
        float bv = (lane16 < 10) ? b7[lane16] : 0.0f;
#pragma unroll
        for (int r = 0; r < 4; ++r) {
            float lg = fmaxf(hacc[r] + bv, 0.0f);
            float vm = (lane16 < 10) ? lg : -1e30f;
#pragma unroll
            for (int off = 8; off; off >>= 1) vm = fmaxf(vm, __shfl_xor(vm, off, 64));
            float ex = (lane16 < 10) ? expf(lg - vm) : 0.0f;
#pragma unroll
            for (int off = 8; off; off >>= 1) ex += __shfl_xor(ex, off, 64);
            float ls = vm + logf(ex);
            if (lane16 < 10) {
                int grow = m0 + w * 16 + lane4 * 4 + r;
                out[(size_t)grow * 10 + lane16] = lg - ls;
            }
        }
    }

    __syncthreads();
    if (tid < 6) {
        float s = went[tid] + went[6 + tid] + went[12 + tid] + went[18 + tid];
        partial[tid * NBLK + blockIdx.x] = s;
    }
}

// ---------------- final entropy mean (deterministic fixed-order) ----------------
__global__ __launch_bounds__(256)
void reduce_kernel(const float* __restrict__ partial, float* __restrict__ out)
{
    __shared__ float s[256];
    const int li = blockIdx.x, tid = threadIdx.x;
    float a = 0.0f;
    for (int i = tid; i < NBLK; i += 256) a += partial[li * NBLK + i];
    s[tid] = a;
    __syncthreads();
    for (int st = 128; st; st >>= 1) {
        if (tid < st) s[tid] += s[tid + st];
        __syncthreads();
    }
    if (tid == 0)
        out[(size_t)BATCH * 10 + li] = s[0] / (float)BATCH + logf((float)BINS);
}

// ---------------- launch ----------------
extern "C" void kernel_launch(void* const* d_in, const int* in_sizes, int n_in,
                              void* d_out, int out_size, void* d_ws, size_t ws_size,
                              hipStream_t stream)
{
    (void)in_sizes; (void)n_in; (void)out_size; (void)ws_size;

    const float* x  = (const float*)d_in[0];
    const float* W1 = (const float*)d_in[1];
    const float* b1 = (const float*)d_in[2];
    const float* W2 = (const float*)d_in[3];
    const float* b2 = (const float*)d_in[4];
    const float* W3 = (const float*)d_in[5];
    const float* b3 = (const float*)d_in[6];
    const float* W4 = (const float*)d_in[7];
    const float* b4 = (const float*)d_in[8];
    const float* W5 = (const float*)d_in[9];
    const float* b5 = (const float*)d_in[10];
    const float* W6 = (const float*)d_in[11];
    const float* b6 = (const float*)d_in[12];
    const float* W7 = (const float*)d_in[13];
    const float* b7 = (const float*)d_in[14];

    char* ws = (char*)d_ws;
    // ws layout (bytes):
    //   0       : W1p  256*832 bf16   = 425984
    //   425984  : Wp   5*256*256 bf16 = 655360
    //   1081344 : W7p  16*256 bf16    = 8192
    //   1089536 : bpad 6*256 f32      = 6144
    //   1095680 : partial 6*1024 f32  = 24576
    __bf16* W1p = (__bf16*)(ws);
    __bf16* Wp  = (__bf16*)(ws + 425984);
    __bf16* W7p = (__bf16*)(ws + 1081344);
    float*  bpad = (float*)(ws + 1089536);
    float*  partial = (float*)(ws + 1095680);
    float*  out = (float*)d_out;

    pad_weights<<<2134, 256, 0, stream>>>(W1, W2, W3, W4, W5, W6, W7,
                                          b1, b2, b3, b4, b5, b6,
                                          W1p, Wp, W7p, bpad);
    mega<<<NBLK, 256, 0, stream>>>(x, W1p, Wp, W7p, bpad, b7, out, partial);
    reduce_kernel<<<6, 256, 0, stream>>>(partial, out);
}